// Round 5
// baseline (964.578 us; speedup 1.0000x reference)
//
#include <hip/hip_runtime.h>
#include <cstdint>

// Problem constants (from reference)
constexpr int G = 4, N = 50000, E = 800000;
constexpr int FIN = 64, HID = 128, FOUT = 64;
constexpr int NB = (N + 1023) / 1024;  // scan blocks per graph = 49

typedef unsigned short ushort;

__device__ __forceinline__ ushort f2bf(float f) {  // RNE
  uint32_t u = __builtin_bit_cast(uint32_t, f);
  u += 0x7FFF + ((u >> 16) & 1);
  return (ushort)(u >> 16);
}
__device__ __forceinline__ float bf2f(ushort h) {
  uint32_t u = (uint32_t)h << 16;
  return __builtin_bit_cast(float, u);
}

// XCD-confined swizzle: block b -> XCD (b&7), 2 XCDs per graph.
// Requires G*N/4 = 50000 blocks; per graph 12500 chunks of 4 nodes.
__device__ __forceinline__ void xcd_map(int b, int& g, int& chunk) {
  int xcd = b & 7;
  int sub = b >> 3;  // 0..6249
  g = xcd >> 1;
  chunk = (xcd & 1) * 6250 + sub;  // 0..12499
}

// ---------------- utility kernels ----------------
__global__ void k_zero_int(int* p, int n) {
  int i = blockIdx.x * blockDim.x + threadIdx.x;
  if (i < n) p[i] = 0;
}

// count in-degree per node AND record each edge's rank within its dst
__global__ void k_deg(const int* __restrict__ ei, int* __restrict__ cnt,
                      int* __restrict__ rank) {
  int i = blockIdx.x * blockDim.x + threadIdx.x;  // over G*E
  if (i >= G * E) return;
  int g = i / E, e = i - g * E;
  int dst = ei[(size_t)g * 2 * E + E + e];
  rank[i] = atomicAdd(&cnt[g * N + dst], 1);
}

// ---- 3-kernel exclusive scan of cnt -> rowptr (per graph) ----
__global__ void k_scan_partial(const int* __restrict__ cnt, int* __restrict__ part) {
  int g = blockIdx.y, b = blockIdx.x, tid = threadIdx.x;
  int base = b * 1024 + tid * 4;
  int s = 0;
#pragma unroll
  for (int k = 0; k < 4; ++k) {
    int i = base + k;
    if (i < N) s += cnt[g * N + i];
  }
  __shared__ int sm[256];
  sm[tid] = s;
  __syncthreads();
  for (int off = 128; off > 0; off >>= 1) {
    if (tid < off) sm[tid] += sm[tid + off];
    __syncthreads();
  }
  if (tid == 0) part[g * NB + b] = sm[0];
}

__global__ void k_scan_mid(int* __restrict__ part, int* __restrict__ rowptr) {
  int g = blockIdx.x;
  if (threadIdx.x != 0) return;
  int run = 0;
  for (int b = 0; b < NB; ++b) {
    int t = part[g * NB + b];
    part[g * NB + b] = run;
    run += t;
  }
  rowptr[g * (N + 1) + N] = run;  // == E
}

// final scan + fused dinv computation
__global__ void k_scan_final(const int* __restrict__ cnt, const int* __restrict__ part,
                             int* __restrict__ rowptr, float* __restrict__ dinv) {
  int g = blockIdx.y, b = blockIdx.x, tid = threadIdx.x;
  int base = b * 1024 + tid * 4;
  int c[4];
  int s = 0;
#pragma unroll
  for (int k = 0; k < 4; ++k) {
    int i = base + k;
    c[k] = (i < N) ? cnt[g * N + i] : 0;
    s += c[k];
  }
  __shared__ int sm[256];
  sm[tid] = s;
  __syncthreads();
  for (int off = 1; off < 256; off <<= 1) {
    int v = (tid >= off) ? sm[tid - off] : 0;
    __syncthreads();
    sm[tid] += v;
    __syncthreads();
  }
  int excl = sm[tid] - s + part[g * NB + b];
#pragma unroll
  for (int k = 0; k < 4; ++k) {
    int i = base + k;
    if (i < N) {
      rowptr[g * (N + 1) + i] = excl;
      dinv[g * N + i] = rsqrtf((float)(c[k] + 1));  // +1 self loop
    }
    excl += c[k];
  }
}

// atomic-free CSR fill: slot = rowptr[dst] + precomputed rank
__global__ void k_fill(const int* __restrict__ ei, const int* __restrict__ rowptr,
                       const int* __restrict__ rank, int* __restrict__ col) {
  int i = blockIdx.x * blockDim.x + threadIdx.x;
  if (i >= G * E) return;
  int g = i / E, e = i - g * E;
  int src = ei[(size_t)g * 2 * E + e];
  int dst = ei[(size_t)g * 2 * E + E + e];
  col[(size_t)g * E + rowptr[g * (N + 1) + dst] + rank[i]] = src;
}

// ---------------- LDS-staged GEMM: columns across waves, lane = row ----------------
// Block = 256 threads = 4 waves, covers 64 rows. X tile staged ONCE in LDS
// (padded row stride K+1 -> (lane+k)%32 bank map, 2 lanes/bank = free).
// Wave w computes columns [w*F/4, (w+1)*F/4) for all 64 rows.
// W index is wave-uniform -> s_load; inner loop = ds_read_b32 + CH v_fmac.
// X is read from HBM exactly once (deterministic, not compiler-dependent).
template <int K, int F, bool PRESCALE, bool BIASELU, bool OUTBF>
__global__ __launch_bounds__(256) void k_gemm_lds(const float* __restrict__ X,
                                                  const float* __restrict__ W,
                                                  const float* __restrict__ dinv,
                                                  const float* __restrict__ bias,
                                                  void* __restrict__ Hout) {
  constexpr int CH = F / 4;  // columns per wave (32 or 16)
  constexpr int PK = K + 1;  // padded LDS row stride
  __shared__ float xs[64 * PK];
  int g = blockIdx.y;
  int R0 = blockIdx.x * 64;
  // stage 64 rows (coalesced global read, conflict-free LDS write)
  for (int idx = threadIdx.x; idx < 64 * K; idx += 256) {
    int r = idx / K, k = idx - r * K;
    int row = R0 + r;
    xs[r * PK + k] = (row < N) ? X[((size_t)g * N + row) * K + k] : 0.f;
  }
  __syncthreads();
  int wv = threadIdx.x >> 6;
  int lane = threadIdx.x & 63;
  int c0 = wv * CH;  // wave-uniform column base
  const float* Wg = W + (size_t)g * K * F;
  const float* xrow = &xs[lane * PK];
  float acc[CH];
#pragma unroll
  for (int c = 0; c < CH; ++c) acc[c] = 0.f;
#pragma unroll 4
  for (int k = 0; k < K; ++k) {
    float xv = xrow[k];
#pragma unroll
    for (int c = 0; c < CH; ++c)
      acc[c] = fmaf(xv, Wg[(size_t)k * F + c0 + c], acc[c]);
  }
  int row = R0 + lane;
  if (row >= N) return;
  if constexpr (PRESCALE) {
    float sc = dinv[g * N + row];
#pragma unroll
    for (int c = 0; c < CH; ++c) acc[c] *= sc;
  }
  if constexpr (BIASELU) {
#pragma unroll
    for (int c = 0; c < CH; ++c) {
      float v = acc[c] + bias[g * F + c0 + c];
      acc[c] = v > 0.f ? v : expm1f(v);
    }
  }
  if constexpr (OUTBF) {
    ushort* opb = (ushort*)Hout + ((size_t)g * N + row) * F + c0;
#pragma unroll
    for (int c4 = 0; c4 < CH; c4 += 4) {
      ushort4 o = {f2bf(acc[c4]), f2bf(acc[c4 + 1]), f2bf(acc[c4 + 2]),
                   f2bf(acc[c4 + 3])};
      *(ushort4*)(opb + c4) = o;
    }
  } else {
    float* op = (float*)Hout + ((size_t)g * N + row) * F + c0;
#pragma unroll
    for (int c4 = 0; c4 < CH; c4 += 4) {
      float4 o = {acc[c4], acc[c4 + 1], acc[c4 + 2], acc[c4 + 3]};
      *(float4*)(op + c4) = o;
    }
  }
}

// ---------------- aggregate-first (layer 1): Z = D^-1/2 (A+I) D^-1/2 X ----------------
// one wave per dst node; F = 64 (1 float/lane); dinv[s] folded in via shfl broadcast
template <int F>
__global__ __launch_bounds__(256) void k_agg_in(const float* __restrict__ X,
                                                const int* __restrict__ rowptr,
                                                const int* __restrict__ col,
                                                const float* __restrict__ dinv,
                                                float* __restrict__ Z) {
  int g, chunk;
  xcd_map(blockIdx.x, g, chunk);
  int d = chunk * 4 + (threadIdx.x >> 6);
  int lane = threadIdx.x & 63;
  const float* hb = X + (size_t)g * N * F;
  const float* dv = dinv + g * N;
  const int* cl = col + (size_t)g * E;
  int rs = rowptr[g * (N + 1) + d];
  int re = rowptr[g * (N + 1) + d + 1];
  float dd = dv[d];
  float acc = dd * hb[(size_t)d * F + lane];  // self loop
  for (int j0 = rs; j0 < re; j0 += 64) {
    int idx = j0 + lane;
    int myc = (idx < re) ? cl[idx] : 0;
    float myd = (idx < re) ? dv[myc] : 0.f;
    int nn = min(64, re - j0);
    int jj = 0;
    for (; jj + 8 <= nn; jj += 8) {
      int s[8];
      float sw[8];
#pragma unroll
      for (int k = 0; k < 8; ++k) {
        s[k] = __shfl(myc, jj + k, 64);
        sw[k] = __shfl(myd, jj + k, 64);
      }
      float v[8];
#pragma unroll
      for (int k = 0; k < 8; ++k) v[k] = hb[(size_t)s[k] * F + lane];
#pragma unroll
      for (int k = 0; k < 8; ++k) acc += sw[k] * v[k];
    }
    for (; jj < nn; ++jj) {
      int s = __shfl(myc, jj, 64);
      float sw = __shfl(myd, jj, 64);
      acc += sw * hb[(size_t)s * F + lane];
    }
  }
  Z[((size_t)g * N + d) * F + lane] = dd * acc;
}

// ---------------- aggregate-last (layer 2): out = ELU(dinv*(sum h2s) + b) ----------------
// h2s rows bf16, already pre-scaled by dinv[s] in the GEMM
template <int F>
__global__ __launch_bounds__(256) void k_agg_out(const ushort* __restrict__ Hsrc,
                                                 const int* __restrict__ rowptr,
                                                 const int* __restrict__ col,
                                                 const float* __restrict__ dinv,
                                                 const float* __restrict__ bias,
                                                 float* __restrict__ out) {
  int g, chunk;
  xcd_map(blockIdx.x, g, chunk);
  int d = chunk * 4 + (threadIdx.x >> 6);
  int lane = threadIdx.x & 63;
  const ushort* hb = Hsrc + (size_t)g * N * F;
  const int* cl = col + (size_t)g * E;
  int rs = rowptr[g * (N + 1) + d];
  int re = rowptr[g * (N + 1) + d + 1];
  float acc = bf2f(hb[(size_t)d * F + lane]);  // self loop
  for (int j0 = rs; j0 < re; j0 += 64) {
    int idx = j0 + lane;
    int myc = (idx < re) ? cl[idx] : 0;
    int nn = min(64, re - j0);
    int jj = 0;
    for (; jj + 8 <= nn; jj += 8) {
      int s[8];
#pragma unroll
      for (int k = 0; k < 8; ++k) s[k] = __shfl(myc, jj + k, 64);
      float v[8];
#pragma unroll
      for (int k = 0; k < 8; ++k) v[k] = bf2f(hb[(size_t)s[k] * F + lane]);
#pragma unroll
      for (int k = 0; k < 8; ++k) acc += v[k];
    }
    for (; jj < nn; ++jj) {
      int s = __shfl(myc, jj, 64);
      acc += bf2f(hb[(size_t)s * F + lane]);
    }
  }
  float p = acc * dinv[g * N + d] + bias[g * F + lane];
  p = p > 0.f ? p : expm1f(p);
  out[((size_t)g * N + d) * F + lane] = p;
}

extern "C" void kernel_launch(void* const* d_in, const int* in_sizes, int n_in,
                              void* d_out, int out_size, void* d_ws, size_t ws_size,
                              hipStream_t stream) {
  const float* x = (const float*)d_in[0];
  const int* ei = (const int*)d_in[1];
  const float* W1 = (const float*)d_in[2];
  const float* b1 = (const float*)d_in[3];
  const float* W2 = (const float*)d_in[4];
  const float* b2 = (const float*)d_in[5];
  float* out = (float*)d_out;

  // Workspace carve-up (~182 MB needed)
  char* p = (char*)d_ws;
  auto alloc = [&](size_t bytes) {
    char* r = p;
    p += (bytes + 255) & ~(size_t)255;
    return r;
  };
  int* cnt = (int*)alloc(sizeof(int) * G * N);
  int* rowptr = (int*)alloc(sizeof(int) * G * (N + 1));
  int* part = (int*)alloc(sizeof(int) * G * NB);
  float* dinv = (float*)alloc(sizeof(float) * G * N);
  int* rank = (int*)alloc(sizeof(int) * (size_t)G * E);            // 12.8 MB
  int* col = (int*)alloc(sizeof(int) * (size_t)G * E);             // 12.8 MB
  float* z = (float*)alloc(sizeof(float) * (size_t)G * N * FIN);   // 51.2 MB
  float* h1 = (float*)alloc(sizeof(float) * (size_t)G * N * HID);  // 102.4 MB
  ushort* h2s = (ushort*)z;  // bf16, 25.6 MB; reuses z (dead after gemm1)

  // 1. CSR build
  k_zero_int<<<(G * N + 255) / 256, 256, 0, stream>>>(cnt, G * N);
  k_deg<<<(G * E + 255) / 256, 256, 0, stream>>>(ei, cnt, rank);
  dim3 sg(NB, G);
  k_scan_partial<<<sg, 256, 0, stream>>>(cnt, part);
  k_scan_mid<<<G, 64, 0, stream>>>(part, rowptr);
  k_scan_final<<<sg, 256, 0, stream>>>(cnt, part, rowptr, dinv);
  k_fill<<<(G * E + 255) / 256, 256, 0, stream>>>(ei, rowptr, rank, col);

  // 2. layer 1: aggregate-first (fp32 gathers on x), then LDS-GEMM+bias+ELU
  k_agg_in<FIN><<<(G * N) / 4, 256, 0, stream>>>(x, rowptr, col, dinv, z);
  dim3 gg((N + 63) / 64, G);
  k_gemm_lds<FIN, HID, false, true, false>
      <<<gg, 256, 0, stream>>>(z, W1, nullptr, b1, h1);

  // 3. layer 2: transform-first 128->64 (pre-scaled, bf16 out), then aggregate
  k_gemm_lds<HID, FOUT, true, false, true>
      <<<gg, 256, 0, stream>>>(h1, W2, dinv, nullptr, h2s);
  k_agg_out<FOUT><<<(G * N) / 4, 256, 0, stream>>>(h2s, rowptr, col, dinv, b2, out);
}

// Round 6
// 689.980 us; speedup vs baseline: 1.3980x; 1.3980x over previous
//
#include <hip/hip_runtime.h>
#include <cstdint>

// Problem constants (from reference)
constexpr int G = 4, N = 50000, E = 800000;
constexpr int FIN = 64, HID = 128, FOUT = 64;
constexpr int NB = (N + 1023) / 1024;  // scan blocks per graph = 49

typedef unsigned short ushort;

__device__ __forceinline__ ushort f2bf(float f) {  // RNE
  uint32_t u = __builtin_bit_cast(uint32_t, f);
  u += 0x7FFF + ((u >> 16) & 1);
  return (ushort)(u >> 16);
}
__device__ __forceinline__ float bf2f(ushort h) {
  uint32_t u = (uint32_t)h << 16;
  return __builtin_bit_cast(float, u);
}

// XCD-confined swizzle: block b -> XCD (b&7), 2 XCDs per graph.
// Requires G*N/4 = 50000 blocks; per graph 12500 chunks of 4 nodes.
__device__ __forceinline__ void xcd_map(int b, int& g, int& chunk) {
  int xcd = b & 7;
  int sub = b >> 3;  // 0..6249
  g = xcd >> 1;
  chunk = (xcd & 1) * 6250 + sub;  // 0..12499
}

// ---------------- utility kernels ----------------
__global__ void k_zero_int(int* p, int n) {
  int i = blockIdx.x * blockDim.x + threadIdx.x;
  if (i < n) p[i] = 0;
}

// count in-degree per node AND record each edge's rank within its dst
__global__ void k_deg(const int* __restrict__ ei, int* __restrict__ cnt,
                      int* __restrict__ rank) {
  int i = blockIdx.x * blockDim.x + threadIdx.x;  // over G*E
  if (i >= G * E) return;
  int g = i / E, e = i - g * E;
  int dst = ei[(size_t)g * 2 * E + E + e];
  rank[i] = atomicAdd(&cnt[g * N + dst], 1);
}

// ---- 3-kernel exclusive scan of cnt -> rowptr (per graph) ----
__global__ void k_scan_partial(const int* __restrict__ cnt, int* __restrict__ part) {
  int g = blockIdx.y, b = blockIdx.x, tid = threadIdx.x;
  int base = b * 1024 + tid * 4;
  int s = 0;
#pragma unroll
  for (int k = 0; k < 4; ++k) {
    int i = base + k;
    if (i < N) s += cnt[g * N + i];
  }
  __shared__ int sm[256];
  sm[tid] = s;
  __syncthreads();
  for (int off = 128; off > 0; off >>= 1) {
    if (tid < off) sm[tid] += sm[tid + off];
    __syncthreads();
  }
  if (tid == 0) part[g * NB + b] = sm[0];
}

__global__ void k_scan_mid(int* __restrict__ part, int* __restrict__ rowptr) {
  int g = blockIdx.x;
  if (threadIdx.x != 0) return;
  int run = 0;
  for (int b = 0; b < NB; ++b) {
    int t = part[g * NB + b];
    part[g * NB + b] = run;
    run += t;
  }
  rowptr[g * (N + 1) + N] = run;  // == E
}

// final scan + fused dinv computation
__global__ void k_scan_final(const int* __restrict__ cnt, const int* __restrict__ part,
                             int* __restrict__ rowptr, float* __restrict__ dinv) {
  int g = blockIdx.y, b = blockIdx.x, tid = threadIdx.x;
  int base = b * 1024 + tid * 4;
  int c[4];
  int s = 0;
#pragma unroll
  for (int k = 0; k < 4; ++k) {
    int i = base + k;
    c[k] = (i < N) ? cnt[g * N + i] : 0;
    s += c[k];
  }
  __shared__ int sm[256];
  sm[tid] = s;
  __syncthreads();
  for (int off = 1; off < 256; off <<= 1) {
    int v = (tid >= off) ? sm[tid - off] : 0;
    __syncthreads();
    sm[tid] += v;
    __syncthreads();
  }
  int excl = sm[tid] - s + part[g * NB + b];
#pragma unroll
  for (int k = 0; k < 4; ++k) {
    int i = base + k;
    if (i < N) {
      rowptr[g * (N + 1) + i] = excl;
      dinv[g * N + i] = rsqrtf((float)(c[k] + 1));  // +1 self loop
    }
    excl += c[k];
  }
}

// atomic-free CSR fill: slot = rowptr[dst] + precomputed rank
__global__ void k_fill(const int* __restrict__ ei, const int* __restrict__ rowptr,
                       const int* __restrict__ rank, int* __restrict__ col) {
  int i = blockIdx.x * blockDim.x + threadIdx.x;
  if (i >= G * E) return;
  int g = i / E, e = i - g * E;
  int src = ei[(size_t)g * 2 * E + e];
  int dst = ei[(size_t)g * 2 * E + E + e];
  col[(size_t)g * E + rowptr[g * (N + 1) + dst] + rank[i]] = src;
}

// ---------------- LDS-staged GEMM: columns across waves, lane = row ----------------
// Block = 256 threads = 4 waves, covers 64 rows. X tile staged ONCE in LDS
// (padded row stride K+1 -> (lane+k)%32 bank map, 2 lanes/bank = free).
// Wave w computes columns [w*F/4, (w+1)*F/4) for all 64 rows.
// c0 forced into an SGPR via readfirstlane so the W address chain is provably
// scalar -> batched s_load through the constant cache on the scalar pipe
// (R5 bug: threadIdx-derived c0 failed divergence analysis -> per-lane
// global_load_dword, VMEM-issue bound, 230 us).
template <int K, int F, bool PRESCALE, bool BIASELU, bool OUTBF>
__global__ __launch_bounds__(256) void k_gemm_lds(const float* __restrict__ X,
                                                  const float* __restrict__ W,
                                                  const float* __restrict__ dinv,
                                                  const float* __restrict__ bias,
                                                  void* __restrict__ Hout) {
  constexpr int CH = F / 4;  // columns per wave (32 or 16)
  constexpr int PK = K + 1;  // padded LDS row stride
  __shared__ float xs[64 * PK];
  int g = blockIdx.y;
  int R0 = blockIdx.x * 64;
  // stage 64 rows (coalesced global read, conflict-free LDS write)
  for (int idx = threadIdx.x; idx < 64 * K; idx += 256) {
    int r = idx / K, k = idx - r * K;
    int row = R0 + r;
    xs[r * PK + k] = (row < N) ? X[((size_t)g * N + row) * K + k] : 0.f;
  }
  __syncthreads();
  int wv = threadIdx.x >> 6;
  int lane = threadIdx.x & 63;
  int c0 = __builtin_amdgcn_readfirstlane(wv * CH);  // SGPR column base
  const float* Wg = W + (size_t)g * K * F;
  const float* xrow = &xs[lane * PK];
  float acc[CH];
#pragma unroll
  for (int c = 0; c < CH; ++c) acc[c] = 0.f;
#pragma unroll 4
  for (int k = 0; k < K; ++k) {
    float xv = xrow[k];
#pragma unroll
    for (int c = 0; c < CH; ++c)
      acc[c] = fmaf(xv, Wg[(size_t)k * F + c0 + c], acc[c]);
  }
  int row = R0 + lane;
  if (row >= N) return;
  if constexpr (PRESCALE) {
    float sc = dinv[g * N + row];
#pragma unroll
    for (int c = 0; c < CH; ++c) acc[c] *= sc;
  }
  if constexpr (BIASELU) {
#pragma unroll
    for (int c = 0; c < CH; ++c) {
      float v = acc[c] + bias[g * F + c0 + c];
      acc[c] = v > 0.f ? v : expm1f(v);
    }
  }
  if constexpr (OUTBF) {
    ushort* opb = (ushort*)Hout + ((size_t)g * N + row) * F + c0;
#pragma unroll
    for (int c4 = 0; c4 < CH; c4 += 4) {
      ushort4 o = {f2bf(acc[c4]), f2bf(acc[c4 + 1]), f2bf(acc[c4 + 2]),
                   f2bf(acc[c4 + 3])};
      *(ushort4*)(opb + c4) = o;
    }
  } else {
    float* op = (float*)Hout + ((size_t)g * N + row) * F + c0;
#pragma unroll
    for (int c4 = 0; c4 < CH; c4 += 4) {
      float4 o = {acc[c4], acc[c4 + 1], acc[c4 + 2], acc[c4 + 3]};
      *(float4*)(op + c4) = o;
    }
  }
}

// ---------------- aggregate-first (layer 1): Z = D^-1/2 (A+I) D^-1/2 X ----------------
// one wave per dst node; F = 64 (1 float/lane); dinv[s] folded in via shfl broadcast
template <int F>
__global__ __launch_bounds__(256) void k_agg_in(const float* __restrict__ X,
                                                const int* __restrict__ rowptr,
                                                const int* __restrict__ col,
                                                const float* __restrict__ dinv,
                                                float* __restrict__ Z) {
  int g, chunk;
  xcd_map(blockIdx.x, g, chunk);
  int d = chunk * 4 + (threadIdx.x >> 6);
  int lane = threadIdx.x & 63;
  const float* hb = X + (size_t)g * N * F;
  const float* dv = dinv + g * N;
  const int* cl = col + (size_t)g * E;
  int rs = rowptr[g * (N + 1) + d];
  int re = rowptr[g * (N + 1) + d + 1];
  float dd = dv[d];
  float acc = dd * hb[(size_t)d * F + lane];  // self loop
  for (int j0 = rs; j0 < re; j0 += 64) {
    int idx = j0 + lane;
    int myc = (idx < re) ? cl[idx] : 0;
    float myd = (idx < re) ? dv[myc] : 0.f;
    int nn = min(64, re - j0);
    int jj = 0;
    for (; jj + 8 <= nn; jj += 8) {
      int s[8];
      float sw[8];
#pragma unroll
      for (int k = 0; k < 8; ++k) {
        s[k] = __shfl(myc, jj + k, 64);
        sw[k] = __shfl(myd, jj + k, 64);
      }
      float v[8];
#pragma unroll
      for (int k = 0; k < 8; ++k) v[k] = hb[(size_t)s[k] * F + lane];
#pragma unroll
      for (int k = 0; k < 8; ++k) acc += sw[k] * v[k];
    }
    for (; jj < nn; ++jj) {
      int s = __shfl(myc, jj, 64);
      float sw = __shfl(myd, jj, 64);
      acc += sw * hb[(size_t)s * F + lane];
    }
  }
  Z[((size_t)g * N + d) * F + lane] = dd * acc;
}

// ---------------- aggregate-last (layer 2): out = ELU(dinv*(sum h2s) + b) ----------------
// h2s rows bf16, already pre-scaled by dinv[s] in the GEMM
template <int F>
__global__ __launch_bounds__(256) void k_agg_out(const ushort* __restrict__ Hsrc,
                                                 const int* __restrict__ rowptr,
                                                 const int* __restrict__ col,
                                                 const float* __restrict__ dinv,
                                                 const float* __restrict__ bias,
                                                 float* __restrict__ out) {
  int g, chunk;
  xcd_map(blockIdx.x, g, chunk);
  int d = chunk * 4 + (threadIdx.x >> 6);
  int lane = threadIdx.x & 63;
  const ushort* hb = Hsrc + (size_t)g * N * F;
  const int* cl = col + (size_t)g * E;
  int rs = rowptr[g * (N + 1) + d];
  int re = rowptr[g * (N + 1) + d + 1];
  float acc = bf2f(hb[(size_t)d * F + lane]);  // self loop
  for (int j0 = rs; j0 < re; j0 += 64) {
    int idx = j0 + lane;
    int myc = (idx < re) ? cl[idx] : 0;
    int nn = min(64, re - j0);
    int jj = 0;
    for (; jj + 8 <= nn; jj += 8) {
      int s[8];
#pragma unroll
      for (int k = 0; k < 8; ++k) s[k] = __shfl(myc, jj + k, 64);
      float v[8];
#pragma unroll
      for (int k = 0; k < 8; ++k) v[k] = bf2f(hb[(size_t)s[k] * F + lane]);
#pragma unroll
      for (int k = 0; k < 8; ++k) acc += v[k];
    }
    for (; jj < nn; ++jj) {
      int s = __shfl(myc, jj, 64);
      acc += bf2f(hb[(size_t)s * F + lane]);
    }
  }
  float p = acc * dinv[g * N + d] + bias[g * F + lane];
  p = p > 0.f ? p : expm1f(p);
  out[((size_t)g * N + d) * F + lane] = p;
}

extern "C" void kernel_launch(void* const* d_in, const int* in_sizes, int n_in,
                              void* d_out, int out_size, void* d_ws, size_t ws_size,
                              hipStream_t stream) {
  const float* x = (const float*)d_in[0];
  const int* ei = (const int*)d_in[1];
  const float* W1 = (const float*)d_in[2];
  const float* b1 = (const float*)d_in[3];
  const float* W2 = (const float*)d_in[4];
  const float* b2 = (const float*)d_in[5];
  float* out = (float*)d_out;

  // Workspace carve-up (~182 MB needed)
  char* p = (char*)d_ws;
  auto alloc = [&](size_t bytes) {
    char* r = p;
    p += (bytes + 255) & ~(size_t)255;
    return r;
  };
  int* cnt = (int*)alloc(sizeof(int) * G * N);
  int* rowptr = (int*)alloc(sizeof(int) * G * (N + 1));
  int* part = (int*)alloc(sizeof(int) * G * NB);
  float* dinv = (float*)alloc(sizeof(float) * G * N);
  int* rank = (int*)alloc(sizeof(int) * (size_t)G * E);            // 12.8 MB
  int* col = (int*)alloc(sizeof(int) * (size_t)G * E);             // 12.8 MB
  float* z = (float*)alloc(sizeof(float) * (size_t)G * N * FIN);   // 51.2 MB
  float* h1 = (float*)alloc(sizeof(float) * (size_t)G * N * HID);  // 102.4 MB
  ushort* h2s = (ushort*)z;  // bf16, 25.6 MB; reuses z (dead after gemm1)

  // 1. CSR build
  k_zero_int<<<(G * N + 255) / 256, 256, 0, stream>>>(cnt, G * N);
  k_deg<<<(G * E + 255) / 256, 256, 0, stream>>>(ei, cnt, rank);
  dim3 sg(NB, G);
  k_scan_partial<<<sg, 256, 0, stream>>>(cnt, part);
  k_scan_mid<<<G, 64, 0, stream>>>(part, rowptr);
  k_scan_final<<<sg, 256, 0, stream>>>(cnt, part, rowptr, dinv);
  k_fill<<<(G * E + 255) / 256, 256, 0, stream>>>(ei, rowptr, rank, col);

  // 2. layer 1: aggregate-first (fp32 gathers on x), then LDS-GEMM+bias+ELU
  k_agg_in<FIN><<<(G * N) / 4, 256, 0, stream>>>(x, rowptr, col, dinv, z);
  dim3 gg((N + 63) / 64, G);
  k_gemm_lds<FIN, HID, false, true, false>
      <<<gg, 256, 0, stream>>>(z, W1, nullptr, b1, h1);

  // 3. layer 2: transform-first 128->64 (pre-scaled, bf16 out), then aggregate
  k_gemm_lds<HID, FOUT, true, false, true>
      <<<gg, 256, 0, stream>>>(h1, W2, dinv, nullptr, h2s);
  k_agg_out<FOUT><<<(G * N) / 4, 256, 0, stream>>>(h2s, rowptr, col, dinv, b2, out);
}